// Round 2
// baseline (2534.854 us; speedup 1.0000x reference)
//
#include <hip/hip_runtime.h>
#include <math.h>

#define BB 128
#define NN 2048
#define CMID 64
#define HH 128
#define NCLS 40
#define CHUNK 128
#define EPSV 1e-5f

__device__ __forceinline__ float fsigmoid(float x) {
    return 1.0f / (1.0f + __expf(-x));
}
__device__ __forceinline__ float ftanh2(float x) {
    return 2.0f / (1.0f + __expf(-2.0f * x)) - 1.0f;
}
__device__ __forceinline__ void fma4(float& a, const float4 w, const float4 v) {
    a = fmaf(w.x, v.x, a);
    a = fmaf(w.y, v.y, a);
    a = fmaf(w.z, v.z, a);
    a = fmaf(w.w, v.w, a);
}

// 1024 threads: unit j = t>>3 (0..127), split s = t&7 (8-way slice of the
// 192-dim concatenated [hc(64); h(128)] operand).  Each thread holds the
// weight slices for ALL FOUR gate rows of its unit: 4*(8+16) = 96 floats.
// One __syncthreads() per timestep (h double-buffered, padded vs conflicts).
__global__ __launch_bounds__(1024, 4)
void lstm_seq_kernel(const float* __restrict__ x,
                     const float* __restrict__ conv_w, const float* __restrict__ conv_b,
                     const float* __restrict__ gamma,  const float* __restrict__ beta,
                     const float* __restrict__ rmean,  const float* __restrict__ rvar,
                     const float* __restrict__ W_ih,   const float* __restrict__ W_hh,
                     const float* __restrict__ b_ih,   const float* __restrict__ b_hh,
                     const float* __restrict__ W_out,  const float* __restrict__ b_out,
                     float* __restrict__ out)
{
    __shared__ float hc_s[CHUNK][CMID];          // 32 KB conv+BN+ReLU chunk
    __shared__ float h_p[2][8][20];              // hidden, padded (20 = 16+4) & dbuf
    __shared__ float cA0[CMID], cA1[CMID], cA2[CMID], cD[CMID];

    const int t = threadIdx.x;
    const int b = blockIdx.x;
    const int j = t >> 3;     // hidden unit 0..127
    const int s = t & 7;      // split 0..7

    // fold conv+BN into per-channel affine (once)
    if (t < CMID) {
        float inv = gamma[t] * rsqrtf(rvar[t] + EPSV);
        cA0[t] = conv_w[t * 3 + 0] * inv;
        cA1[t] = conv_w[t * 3 + 1] * inv;
        cA2[t] = conv_w[t * 3 + 2] * inv;
        cD[t]  = (conv_b[t] - rmean[t]) * inv + beta[t];
    }
    if (t < 2 * 8 * 20) ((float*)h_p)[t] = 0.0f;

    // per-thread register weights: 24 float4 = 96 VGPRs
    float4 wih[4][2];
    float4 whh[4][4];
    float bias[4];
    #pragma unroll
    for (int g = 0; g < 4; ++g) {
        const int r = g * HH + j;
        const float* pih = W_ih + (size_t)r * CMID + s * 8;
        wih[g][0] = *(const float4*)(pih);
        wih[g][1] = *(const float4*)(pih + 4);
        const float* phh = W_hh + (size_t)r * HH + s * 16;
        #pragma unroll
        for (int i2 = 0; i2 < 4; ++i2) whh[g][i2] = *(const float4*)(phh + 4 * i2);
        bias[g] = b_ih[r] + b_hh[r];
    }

    float c_reg = 0.0f;
    const float* xb = x + (size_t)b * NN * 3;

    for (int ch = 0; ch < NN / CHUNK; ++ch) {
        const int base = ch * CHUNK;
        __syncthreads();   // prior chunk's hc reads done; coefs visible (1st iter)

        // ---- precompute hc for this chunk (barrier-free parallel work) ----
        #pragma unroll
        for (int i = 0; i < (CHUNK * CMID) / 1024; ++i) {   // 8 iters
            int v  = i * 1024 + t;
            int n  = v >> 6;        // wave-uniform
            int cc = v & 63;
            float x0 = xb[(base + n) * 3 + 0];
            float x1 = xb[(base + n) * 3 + 1];
            float x2 = xb[(base + n) * 3 + 2];
            float hcv = cD[cc] + cA0[cc] * x0 + cA1[cc] * x1 + cA2[cc] * x2;
            hc_s[n][cc] = fmaxf(hcv, 0.0f);
        }
        __syncthreads();

        // ---- recurrence: ONE barrier per step ----
        for (int k = 0; k < CHUNK; ++k) {
            const int p = (base + k) & 1;
            float a0 = 0.f, a1 = 0.f, a2 = 0.f, a3 = 0.f;

            const float4* hcp = (const float4*)(&hc_s[k][s * 8]);
            const float4* hp4 = (const float4*)(&h_p[p][s][0]);

            float4 v0 = hcp[0];
            float4 v1 = hcp[1];
            fma4(a0, wih[0][0], v0); fma4(a1, wih[1][0], v0);
            fma4(a2, wih[2][0], v0); fma4(a3, wih[3][0], v0);
            fma4(a0, wih[0][1], v1); fma4(a1, wih[1][1], v1);
            fma4(a2, wih[2][1], v1); fma4(a3, wih[3][1], v1);

            #pragma unroll
            for (int i2 = 0; i2 < 4; ++i2) {
                float4 u = hp4[i2];
                fma4(a0, whh[0][i2], u); fma4(a1, whh[1][i2], u);
                fma4(a2, whh[2][i2], u); fma4(a3, whh[3][i2], u);
            }

            // butterfly over the 8 split-lanes -> all lanes hold all 4 sums
            #pragma unroll
            for (int m = 1; m <= 4; m <<= 1) {
                a0 += __shfl_xor(a0, m);
                a1 += __shfl_xor(a1, m);
                a2 += __shfl_xor(a2, m);
                a3 += __shfl_xor(a3, m);
            }

            float gi = fsigmoid(a0 + bias[0]);
            float gf = fsigmoid(a1 + bias[1]);
            float gg = ftanh2(a2 + bias[2]);
            float go = fsigmoid(a3 + bias[3]);
            c_reg = gf * c_reg + gi * gg;          // identical in all 8 replicas
            float hv = go * ftanh2(c_reg);

            if (s == 0) h_p[p ^ 1][j >> 4][j & 15] = hv;
            __syncthreads();
        }
    }

    // ---- classifier head (final h sits in parity-0 buffer after 2048 steps) ----
    if (t < NCLS) {
        float acc = b_out[t];
        const float* wr = W_out + (size_t)t * HH;
        #pragma unroll
        for (int jj = 0; jj < HH; ++jj)
            acc = fmaf(wr[jj], h_p[0][jj >> 4][jj & 15], acc);
        out[(size_t)b * NCLS + t] = acc;
    }
}

extern "C" void kernel_launch(void* const* d_in, const int* in_sizes, int n_in,
                              void* d_out, int out_size, void* d_ws, size_t ws_size,
                              hipStream_t stream) {
    const float* x      = (const float*)d_in[0];
    const float* conv_w = (const float*)d_in[1];
    const float* conv_b = (const float*)d_in[2];
    const float* gamma  = (const float*)d_in[3];
    const float* beta   = (const float*)d_in[4];
    const float* rmean  = (const float*)d_in[5];
    const float* rvar   = (const float*)d_in[6];
    const float* W_ih   = (const float*)d_in[7];
    const float* W_hh   = (const float*)d_in[8];
    const float* b_ih   = (const float*)d_in[9];
    const float* b_hh   = (const float*)d_in[10];
    const float* W_out  = (const float*)d_in[11];
    const float* b_out  = (const float*)d_in[12];
    float* out = (float*)d_out;

    lstm_seq_kernel<<<BB, 1024, 0, stream>>>(x, conv_w, conv_b, gamma, beta,
                                             rmean, rvar, W_ih, W_hh, b_ih, b_hh,
                                             W_out, b_out, out);
}

// Round 5
// 1927.339 us; speedup vs baseline: 1.3152x; 1.3152x over previous
//
#include <hip/hip_runtime.h>
#include <math.h>

#define BB 128
#define NN 2048
#define CMID 64
#define HH 128
#define NCLS 40
#define CHUNK 128
#define EPSV 1e-5f

// padded LDS geometry (bank-conflict-free across the 4 slices)
#define HCP 80           // hc row stride in floats (slice s at +s*20)
#define HP  36           // h slice stride in floats (slice s at +s*36; 144B = 9*16 aligned)

__device__ __forceinline__ float fsigmoid(float x) {
    return 1.0f / (1.0f + __expf(-x));
}
__device__ __forceinline__ float ftanh2(float x) {
    return 2.0f / (1.0f + __expf(-2.0f * x)) - 1.0f;
}
__device__ __forceinline__ void fma4(float& a, const float4 w, const float4 v) {
    a = fmaf(w.x, v.x, a);
    a = fmaf(w.y, v.y, a);
    a = fmaf(w.z, v.z, a);
    a = fmaf(w.w, v.w, a);
}

// 512 threads: thread = (unit j = t>>2, slice s = t&3).
// Thread holds ALL FOUR gate rows of unit j over its 48-dim slice
// (16 hc dims + 32 h dims) in fp32: 48 float4 = 192 VGPRs, resident under
// the 256-VGPR cap from waves_per_eu(2,2).  One barrier per step.
// NOTE: bias must be added AFTER the lane-reduce (round-4 bug: 4x bias).
__global__ __attribute__((amdgpu_flat_work_group_size(512, 512),
                          amdgpu_waves_per_eu(2, 2)))
void lstm_seq_kernel(const float* __restrict__ x,
                     const float* __restrict__ conv_w, const float* __restrict__ conv_b,
                     const float* __restrict__ gamma,  const float* __restrict__ beta,
                     const float* __restrict__ rmean,  const float* __restrict__ rvar,
                     const float* __restrict__ W_ih,   const float* __restrict__ W_hh,
                     const float* __restrict__ b_ih,   const float* __restrict__ b_hh,
                     const float* __restrict__ W_out,  const float* __restrict__ b_out,
                     float* __restrict__ out)
{
    __shared__ float hc_s[CHUNK * HCP];      // 40 KB  conv+BN+ReLU chunk (padded)
    __shared__ float h_s[2][4 * HP];         // 1.1 KB hidden, padded + double-buffered
    __shared__ float cA0[CMID], cA1[CMID], cA2[CMID], cD[CMID];

    const int t = threadIdx.x;
    const int b = blockIdx.x;
    const int j = t >> 2;   // hidden unit 0..127
    const int s = t & 3;    // slice 0..3

    if (t < CMID) {
        float inv = gamma[t] * rsqrtf(rvar[t] + EPSV);
        cA0[t] = conv_w[t * 3 + 0] * inv;
        cA1[t] = conv_w[t * 3 + 1] * inv;
        cA2[t] = conv_w[t * 3 + 2] * inv;
        cD[t]  = (conv_b[t] - rmean[t]) * inv + beta[t];
    }
    if (t < 2 * 4 * HP) ((float*)h_s)[t] = 0.0f;

    // ---- per-thread fp32 weights: 48 float4 = 192 VGPRs ----
    float4 wih[4][4];   // 16 ih dims per gate row
    float4 whh[4][8];   // 32 hh dims per gate row
    float  bias[4];
    #pragma unroll
    for (int g = 0; g < 4; ++g) {
        const int r = g * HH + j;
        const float* pih = W_ih + (size_t)r * CMID + s * 16;
        #pragma unroll
        for (int i = 0; i < 4; ++i) wih[g][i] = *(const float4*)(pih + 4 * i);
        const float* phh = W_hh + (size_t)r * HH + s * 32;
        #pragma unroll
        for (int i = 0; i < 8; ++i) whh[g][i] = *(const float4*)(phh + 4 * i);
        bias[g] = b_ih[r] + b_hh[r];
    }

    float c_reg = 0.0f;
    const float* xb = x + (size_t)b * NN * 3;

    for (int ch = 0; ch < NN / CHUNK; ++ch) {
        const int base = ch * CHUNK;
        __syncthreads();   // prior chunk fully consumed; init writes visible

        // ---- precompute padded fp32 hc for this chunk ----
        #pragma unroll
        for (int i = 0; i < (CHUNK * CMID) / 512; ++i) {   // 16 iters
            int v  = i * 512 + t;
            int n  = v >> 6;          // wave-uniform
            int cc = v & 63;
            float x0 = xb[(base + n) * 3 + 0];
            float x1 = xb[(base + n) * 3 + 1];
            float x2 = xb[(base + n) * 3 + 2];
            float hcv = fmaxf(cD[cc] + cA0[cc] * x0 + cA1[cc] * x1 + cA2[cc] * x2, 0.0f);
            hc_s[n * HCP + (cc >> 4) * 20 + (cc & 15)] = hcv;
        }
        __syncthreads();

        // ---- recurrence: one barrier per step ----
        for (int k = 0; k < CHUNK; ++k) {
            const int p = (base + k) & 1;
            float a0 = 0.f, a1 = 0.f, a2 = 0.f, a3 = 0.f;

            const float4* hcp = (const float4*)&hc_s[k * HCP + s * 20];  // 4 x 16B
            const float4* hp  = (const float4*)&h_s[p][s * HP];          // 8 x 16B

            #pragma unroll
            for (int i = 0; i < 4; ++i) {
                float4 v = hcp[i];
                fma4(a0, wih[0][i], v); fma4(a1, wih[1][i], v);
                fma4(a2, wih[2][i], v); fma4(a3, wih[3][i], v);
            }
            #pragma unroll
            for (int i = 0; i < 8; ++i) {
                float4 u = hp[i];
                fma4(a0, whh[0][i], u); fma4(a1, whh[1][i], u);
                fma4(a2, whh[2][i], u); fma4(a3, whh[3][i], u);
            }

            // reduce across the 4 slice-lanes (masks 1,2 -> DPP quad-perm)
            #pragma unroll
            for (int m = 1; m <= 2; m <<= 1) {
                a0 += __shfl_xor(a0, m);
                a1 += __shfl_xor(a1, m);
                a2 += __shfl_xor(a2, m);
                a3 += __shfl_xor(a3, m);
            }

            // bias AFTER the reduce (each lane would otherwise contribute it)
            float gi = fsigmoid(a0 + bias[0]);
            float gf = fsigmoid(a1 + bias[1]);
            float gg = ftanh2(a2 + bias[2]);
            float go = fsigmoid(a3 + bias[3]);
            c_reg = gf * c_reg + gi * gg;            // identical in all 4 replicas
            float hv = go * ftanh2(c_reg);

            if (s == 0) h_s[p ^ 1][(j >> 5) * HP + (j & 31)] = hv;
            __syncthreads();
        }
    }

    // ---- classifier head: final h is in parity-0 buffer ----
    if (t < NCLS) {
        float acc = b_out[t];
        const float* wr = W_out + (size_t)t * HH;
        #pragma unroll
        for (int jj = 0; jj < HH; ++jj)
            acc = fmaf(wr[jj], h_s[0][(jj >> 5) * HP + (jj & 31)], acc);
        out[(size_t)b * NCLS + t] = acc;
    }
}

extern "C" void kernel_launch(void* const* d_in, const int* in_sizes, int n_in,
                              void* d_out, int out_size, void* d_ws, size_t ws_size,
                              hipStream_t stream) {
    const float* x      = (const float*)d_in[0];
    const float* conv_w = (const float*)d_in[1];
    const float* conv_b = (const float*)d_in[2];
    const float* gamma  = (const float*)d_in[3];
    const float* beta   = (const float*)d_in[4];
    const float* rmean  = (const float*)d_in[5];
    const float* rvar   = (const float*)d_in[6];
    const float* W_ih   = (const float*)d_in[7];
    const float* W_hh   = (const float*)d_in[8];
    const float* b_ih   = (const float*)d_in[9];
    const float* b_hh   = (const float*)d_in[10];
    const float* W_out  = (const float*)d_in[11];
    const float* b_out  = (const float*)d_in[12];
    float* out = (float*)d_out;

    lstm_seq_kernel<<<BB, 512, 0, stream>>>(x, conv_w, conv_b, gamma, beta,
                                            rmean, rvar, W_ih, W_hh, b_ih, b_hh,
                                            W_out, b_out, out);
}